// Round 8
// baseline (63647.742 us; speedup 1.0000x reference)
//
#include <hip/hip_runtime.h>

// LSTM T=4096, I=512, H=2048, 4H=8192, O=1, fp32.
// R8: 128 WGs x 1024 thr (16 hidden/WG, 64 gate rows) — halves poll storm
// and straggler set. Sticky per-chunk poll (monotonic tags). Tail on wave 0.
// h published as tagged u64 (fp32bits<<32 | step), parity double buffer.

#define T_STEPS 4096
#define HID     2048
#define GATES   8192
#define KIN     512
#define NWG     128
#define NTHR    1024
#define XG_BYTES ((size_t)T_STEPS * GATES * 4)
#define HCOM_BYTES (2UL * HID * 8UL)

typedef float v2f __attribute__((ext_vector_type(2)));

__device__ __forceinline__ float u2f(unsigned int u) {
    union { unsigned int u; float f; } x; x.u = u; return x.f;
}
__device__ __forceinline__ float fast_sigmoid(float x) {
    return 1.f / (1.f + __expf(-x));
}
__device__ __forceinline__ float fast_tanh(float x) {
    return 2.f / (1.f + __expf(-2.f * x)) - 1.f;
}

// ---------------- xg = X @ Wih^T + (bih+bhh), fp32 tiled ----------------
__global__ __launch_bounds__(256) void gemm_xg(const float* __restrict__ A,
                                               const float* __restrict__ B,
                                               const float* __restrict__ bih,
                                               const float* __restrict__ bhh,
                                               float* __restrict__ C) {
    __shared__ float As[32][68];
    __shared__ float Bs[32][68];
    const int t  = threadIdx.x;
    const int tx = t & 15, ty = t >> 4;
    const int m0 = blockIdx.y * 64, n0 = blockIdx.x * 64;
    const int sr = t >> 3, sc = (t & 7) * 4;

    float c[4][4] = {};
    for (int k0 = 0; k0 < KIN; k0 += 32) {
        float4 a0 = *(const float4*)(A + (size_t)(m0 + sr)      * KIN + k0 + sc);
        float4 a1 = *(const float4*)(A + (size_t)(m0 + sr + 32) * KIN + k0 + sc);
        float4 b0 = *(const float4*)(B + (size_t)(n0 + sr)      * KIN + k0 + sc);
        float4 b1 = *(const float4*)(B + (size_t)(n0 + sr + 32) * KIN + k0 + sc);
        __syncthreads();
        As[sc+0][sr] = a0.x; As[sc+1][sr] = a0.y; As[sc+2][sr] = a0.z; As[sc+3][sr] = a0.w;
        As[sc+0][sr+32] = a1.x; As[sc+1][sr+32] = a1.y; As[sc+2][sr+32] = a1.z; As[sc+3][sr+32] = a1.w;
        Bs[sc+0][sr] = b0.x; Bs[sc+1][sr] = b0.y; Bs[sc+2][sr] = b0.z; Bs[sc+3][sr] = b0.w;
        Bs[sc+0][sr+32] = b1.x; Bs[sc+1][sr+32] = b1.y; Bs[sc+2][sr+32] = b1.z; Bs[sc+3][sr+32] = b1.w;
        __syncthreads();
#pragma unroll
        for (int kk = 0; kk < 32; ++kk) {
            float4 av = *(const float4*)&As[kk][ty * 4];
            float4 bv = *(const float4*)&Bs[kk][tx * 4];
            c[0][0] = fmaf(av.x, bv.x, c[0][0]); c[0][1] = fmaf(av.x, bv.y, c[0][1]);
            c[0][2] = fmaf(av.x, bv.z, c[0][2]); c[0][3] = fmaf(av.x, bv.w, c[0][3]);
            c[1][0] = fmaf(av.y, bv.x, c[1][0]); c[1][1] = fmaf(av.y, bv.y, c[1][1]);
            c[1][2] = fmaf(av.y, bv.z, c[1][2]); c[1][3] = fmaf(av.y, bv.w, c[1][3]);
            c[2][0] = fmaf(av.z, bv.x, c[2][0]); c[2][1] = fmaf(av.z, bv.y, c[2][1]);
            c[2][2] = fmaf(av.z, bv.z, c[2][2]); c[2][3] = fmaf(av.z, bv.w, c[2][3]);
            c[3][0] = fmaf(av.w, bv.x, c[3][0]); c[3][1] = fmaf(av.w, bv.y, c[3][1]);
            c[3][2] = fmaf(av.w, bv.z, c[3][2]); c[3][3] = fmaf(av.w, bv.w, c[3][3]);
        }
    }
    const int col = n0 + tx * 4;
    float4 bias;
    bias.x = bih[col]   + bhh[col];
    bias.y = bih[col+1] + bhh[col+1];
    bias.z = bih[col+2] + bhh[col+2];
    bias.w = bih[col+3] + bhh[col+3];
#pragma unroll
    for (int i = 0; i < 4; ++i) {
        float4 o;
        o.x = c[i][0] + bias.x; o.y = c[i][1] + bias.y;
        o.z = c[i][2] + bias.z; o.w = c[i][3] + bias.w;
        *(float4*)(C + (size_t)(m0 + ty * 4 + i) * GATES + col) = o;
    }
}

// ---------------- persistent recurrence ----------------
// 128 WGs x 1024 thr. WG owns hidden [16b,16b+16) = 64 gate rows.
// kc=t&127 (k subset {g*128+kc}), rg=t>>7 (0..7), 8 rows each:
// local row r = rg*8+m, q = r>>4 (gate), jj = r&15.
// Waves 0-1 poll + LDS rebroadcast; tail (reduce/gates/publish) on wave 0.
template<int USE_XG>
__global__ __launch_bounds__(NTHR, 1) void lstm_rec(
    const float* __restrict__ X,
    const float* __restrict__ Wih,
    const float* __restrict__ xg,
    const float* __restrict__ Whh,
    const float* __restrict__ bih,
    const float* __restrict__ bhh,
    unsigned long long* __restrict__ hcom)
{
    const int t  = threadIdx.x;
    const int kc = t & 127;
    const int rg = t >> 7;
    const int j0 = blockIdx.x * 16;

    // register-resident W_hh slice: 8 rows x 16 cols, packed as float2 over g
    v2f whh2[8][8];
#pragma unroll
    for (int m = 0; m < 8; ++m) {
        const int r = rg * 8 + m;                       // local row 0..63
        const int grow = (r >> 4) * HID + j0 + (r & 15);
        const float* wr = Whh + (size_t)grow * HID + kc;
#pragma unroll
        for (int j = 0; j < 8; ++j) {
            v2f p; p.x = wr[(2 * j) * 128]; p.y = wr[(2 * j + 1) * 128];
            whh2[m][j] = p;
        }
    }
    float wih[8][4];
    if (!USE_XG) {
#pragma unroll
        for (int m = 0; m < 8; ++m) {
            const int r = rg * 8 + m;
            const int grow = (r >> 4) * HID + j0 + (r & 15);
            float4 vx = *(const float4*)(Wih + (size_t)grow * KIN + kc * 4);
            wih[m][0] = vx.x; wih[m][1] = vx.y; wih[m][2] = vx.z; wih[m][3] = vx.w;
        }
    }

    // tail wave: bias + xg row index for local row t (t<64)
    float brow = 0.f;
    int growt = 0;
    if (t < 64) {
        growt = (t >> 4) * HID + j0 + (t & 15);
        brow = bih[growt] + bhh[growt];
    }

    __shared__ float hshare[HID];
    __shared__ float part[64 * 132];
    float c_state = 0.f;

    for (int s = 0; s < T_STEPS; ++s) {
        // tail rows prefetch xg before the poll — hides HBM/LLC latency
        float xgv = 0.f;
        if (USE_XG && t < 64)
            xgv = xg[(size_t)s * GATES + growt];

        v2f hv2[8];
        if (t < 128) {
            // waves 0-1 poll 16 tagged words (parity s&1); sticky per-chunk
            const unsigned long long* hp = hcom + (size_t)(s & 1) * HID;
            unsigned long long v[16];
            int pend = 0xffff;
            int guard = 1 << 18;
            for (;;) {
#pragma unroll
                for (int g = 0; g < 16; ++g) {
                    if (pend & (1 << g))
                        v[g] = __hip_atomic_load(hp + g * 128 + kc, __ATOMIC_RELAXED,
                                                 __HIP_MEMORY_SCOPE_AGENT);
                }
                int np = 0;
#pragma unroll
                for (int g = 0; g < 16; ++g)
                    if ((unsigned int)v[g] < (unsigned int)s) np |= (1 << g);
                pend = np;
                if (!np || --guard <= 0) break;
                __builtin_amdgcn_s_sleep(1);   // rate-limit the poll storm
            }
#pragma unroll
            for (int j = 0; j < 8; ++j) {
                v2f p;
                p.x = u2f((unsigned int)(v[2 * j] >> 32));
                p.y = u2f((unsigned int)(v[2 * j + 1] >> 32));
                hv2[j] = p;
                hshare[(2 * j) * 128 + kc]     = p.x;
                hshare[(2 * j + 1) * 128 + kc] = p.y;
            }
        }
        __syncthreads();                     // B1: hshare ready
        if (t >= 128) {
#pragma unroll
            for (int j = 0; j < 8; ++j) {
                v2f p;
                p.x = hshare[(2 * j) * 128 + kc];
                p.y = hshare[(2 * j + 1) * 128 + kc];
                hv2[j] = p;
            }
        }

        v2f acc2[8];
        if (!USE_XG) {
            float4 x4 = *(const float4*)(X + (size_t)s * KIN + kc * 4);
#pragma unroll
            for (int m = 0; m < 8; ++m) {
                float a = wih[m][0] * x4.x;
                a = fmaf(wih[m][1], x4.y, a);
                a = fmaf(wih[m][2], x4.z, a);
                a = fmaf(wih[m][3], x4.w, a);
                v2f z; z.x = a; z.y = 0.f; acc2[m] = z;
            }
        } else {
#pragma unroll
            for (int m = 0; m < 8; ++m) { v2f z; z.x = 0.f; z.y = 0.f; acc2[m] = z; }
        }

        // packed dot: 64 v_pk_fma_f32 per thread
#pragma unroll
        for (int m = 0; m < 8; ++m) {
            v2f a = acc2[m];
#pragma unroll
            for (int j = 0; j < 8; ++j)
                a = __builtin_elementwise_fma(whh2[m][j], hv2[j], a);
            acc2[m] = a;
        }
#pragma unroll
        for (int m = 0; m < 8; ++m)
            part[(rg * 8 + m) * 132 + kc] = acc2[m].x + acc2[m].y;
        __syncthreads();                     // B2: partials ready

        // tail: wave 0 — thread t (t<64) reduces row t's 128 partials
        if (t < 64) {
            const float4* p4 = (const float4*)(part + t * 132);
            float s0 = 0.f, s1 = 0.f, s2 = 0.f, s3 = 0.f;
#pragma unroll
            for (int i = 0; i < 32; ++i) {
                float4 pv = p4[i];
                s0 += pv.x; s1 += pv.y; s2 += pv.z; s3 += pv.w;
            }
            float sum = ((s0 + s1) + (s2 + s3)) + brow + xgv;
            // rows: q = t>>4, jj = t&15; gather gates f,g,o onto t<16
            const float a1 = __shfl_down(sum, 16, 64);
            const float a2 = __shfl_down(sum, 32, 64);
            const float a3 = __shfl_down(sum, 48, 64);
            if (t < 16) {
                const float i_s = fast_sigmoid(sum);   // gate i (row t)
                const float f_s = fast_sigmoid(a1);    // gate f (row 16+t)
                const float g_t = fast_tanh(a2);       // gate g (row 32+t)
                const float o_s = fast_sigmoid(a3);    // gate o (row 48+t)
                c_state = f_s * c_state + i_s * g_t;
                const float h = o_s * fast_tanh(c_state);
                const unsigned long long pk =
                    ((unsigned long long)__float_as_uint(h) << 32) | (unsigned int)(s + 1);
                __hip_atomic_store(&hcom[(size_t)((s + 1) & 1) * HID + j0 + t], pk,
                                   __ATOMIC_RELAXED, __HIP_MEMORY_SCOPE_AGENT);
            }
        }
        // reuse safety: part(s+1)/hshare(s+1) writes are gated by poll(s+1),
        // which requires OWN publish(s+1), issued after all reads of part(s);
        // hshare(s) reads precede B2(s).
    }
}

// ---------------- out[0] = h_T . W_lin + b_lin ----------------
__global__ __launch_bounds__(256) void final_linear(const unsigned long long* __restrict__ hcom,
                                                    const float* __restrict__ Wlin,
                                                    const float* __restrict__ blin,
                                                    float* __restrict__ out) {
    __shared__ float red[4];
    const int t = threadIdx.x;
    float a = 0.f;
#pragma unroll
    for (int e = 0; e < 8; ++e) {
        const int idx = t * 8 + e;
        a = fmaf(Wlin[idx], u2f((unsigned int)(hcom[idx] >> 32)), a);
    }
#pragma unroll
    for (int m = 1; m < 64; m <<= 1) a += __shfl_xor(a, m, 64);
    if ((t & 63) == 0) red[t >> 6] = a;
    __syncthreads();
    if (t == 0) out[0] = red[0] + red[1] + red[2] + red[3] + blin[0];
}

extern "C" void kernel_launch(void* const* d_in, const int* in_sizes, int n_in,
                              void* d_out, int out_size, void* d_ws, size_t ws_size,
                              hipStream_t stream) {
    const float* X    = (const float*)d_in[0];
    const float* Wih  = (const float*)d_in[1];
    const float* Whh  = (const float*)d_in[2];
    const float* bih  = (const float*)d_in[3];
    const float* bhh  = (const float*)d_in[4];
    const float* Wlin = (const float*)d_in[5];
    const float* blin = (const float*)d_in[6];
    float* out = (float*)d_out;

    char* ws = (char*)d_ws;
    const bool big = ws_size >= XG_BYTES + HCOM_BYTES;

    if (big) {
        float* xg = (float*)ws;
        unsigned long long* hcom = (unsigned long long*)(ws + XG_BYTES);
        (void)hipMemsetAsync(hcom, 0, HCOM_BYTES, stream);
        gemm_xg<<<dim3(GATES / 64, T_STEPS / 64), 256, 0, stream>>>(X, Wih, bih, bhh, xg);
        lstm_rec<1><<<dim3(NWG), dim3(NTHR), 0, stream>>>(X, Wih, xg, Whh, bih, bhh, hcom);
        final_linear<<<1, 256, 0, stream>>>(hcom, Wlin, blin, out);
    } else {
        unsigned long long* hcom = (unsigned long long*)ws;
        (void)hipMemsetAsync(hcom, 0, HCOM_BYTES, stream);
        lstm_rec<0><<<dim3(NWG), dim3(NTHR), 0, stream>>>(X, Wih, nullptr, Whh, bih, bhh, hcom);
        final_linear<<<1, 256, 0, stream>>>(hcom, Wlin, blin, out);
    }
}

// Round 9
// 12738.850 us; speedup vs baseline: 4.9963x; 4.9963x over previous
//
#include <hip/hip_runtime.h>

// LSTM T=4096, I=512, H=2048, 4H=8192, O=1, fp32.
// R9 = R7 exactly (256 WGs x 512 thr — known-good VGPR allocation, tail on
// wave 0, s_sleep(1), fast_tanh) + sticky per-chunk poll (monotonic tags).
// R8 lesson: 1024-thr WGs spill the weight array (VGPR 104->64, FETCH 77GB).
// h published as tagged u64 (fp32bits<<32 | step), parity double buffer.

#define T_STEPS 4096
#define HID     2048
#define GATES   8192
#define KIN     512
#define NWG     256
#define NTHR    512
#define XG_BYTES ((size_t)T_STEPS * GATES * 4)
#define HCOM_BYTES (2UL * HID * 8UL)

typedef float v2f __attribute__((ext_vector_type(2)));

__device__ __forceinline__ float u2f(unsigned int u) {
    union { unsigned int u; float f; } x; x.u = u; return x.f;
}
__device__ __forceinline__ float fast_sigmoid(float x) {
    return 1.f / (1.f + __expf(-x));
}
__device__ __forceinline__ float fast_tanh(float x) {
    return 2.f / (1.f + __expf(-2.f * x)) - 1.f;
}

// ---------------- xg = X @ Wih^T + (bih+bhh), fp32 tiled ----------------
__global__ __launch_bounds__(256) void gemm_xg(const float* __restrict__ A,
                                               const float* __restrict__ B,
                                               const float* __restrict__ bih,
                                               const float* __restrict__ bhh,
                                               float* __restrict__ C) {
    __shared__ float As[32][68];
    __shared__ float Bs[32][68];
    const int t  = threadIdx.x;
    const int tx = t & 15, ty = t >> 4;
    const int m0 = blockIdx.y * 64, n0 = blockIdx.x * 64;
    const int sr = t >> 3, sc = (t & 7) * 4;

    float c[4][4] = {};
    for (int k0 = 0; k0 < KIN; k0 += 32) {
        float4 a0 = *(const float4*)(A + (size_t)(m0 + sr)      * KIN + k0 + sc);
        float4 a1 = *(const float4*)(A + (size_t)(m0 + sr + 32) * KIN + k0 + sc);
        float4 b0 = *(const float4*)(B + (size_t)(n0 + sr)      * KIN + k0 + sc);
        float4 b1 = *(const float4*)(B + (size_t)(n0 + sr + 32) * KIN + k0 + sc);
        __syncthreads();
        As[sc+0][sr] = a0.x; As[sc+1][sr] = a0.y; As[sc+2][sr] = a0.z; As[sc+3][sr] = a0.w;
        As[sc+0][sr+32] = a1.x; As[sc+1][sr+32] = a1.y; As[sc+2][sr+32] = a1.z; As[sc+3][sr+32] = a1.w;
        Bs[sc+0][sr] = b0.x; Bs[sc+1][sr] = b0.y; Bs[sc+2][sr] = b0.z; Bs[sc+3][sr] = b0.w;
        Bs[sc+0][sr+32] = b1.x; Bs[sc+1][sr+32] = b1.y; Bs[sc+2][sr+32] = b1.z; Bs[sc+3][sr+32] = b1.w;
        __syncthreads();
#pragma unroll
        for (int kk = 0; kk < 32; ++kk) {
            float4 av = *(const float4*)&As[kk][ty * 4];
            float4 bv = *(const float4*)&Bs[kk][tx * 4];
            c[0][0] = fmaf(av.x, bv.x, c[0][0]); c[0][1] = fmaf(av.x, bv.y, c[0][1]);
            c[0][2] = fmaf(av.x, bv.z, c[0][2]); c[0][3] = fmaf(av.x, bv.w, c[0][3]);
            c[1][0] = fmaf(av.y, bv.x, c[1][0]); c[1][1] = fmaf(av.y, bv.y, c[1][1]);
            c[1][2] = fmaf(av.y, bv.z, c[1][2]); c[1][3] = fmaf(av.y, bv.w, c[1][3]);
            c[2][0] = fmaf(av.z, bv.x, c[2][0]); c[2][1] = fmaf(av.z, bv.y, c[2][1]);
            c[2][2] = fmaf(av.z, bv.z, c[2][2]); c[2][3] = fmaf(av.z, bv.w, c[2][3]);
            c[3][0] = fmaf(av.w, bv.x, c[3][0]); c[3][1] = fmaf(av.w, bv.y, c[3][1]);
            c[3][2] = fmaf(av.w, bv.z, c[3][2]); c[3][3] = fmaf(av.w, bv.w, c[3][3]);
        }
    }
    const int col = n0 + tx * 4;
    float4 bias;
    bias.x = bih[col]   + bhh[col];
    bias.y = bih[col+1] + bhh[col+1];
    bias.z = bih[col+2] + bhh[col+2];
    bias.w = bih[col+3] + bhh[col+3];
#pragma unroll
    for (int i = 0; i < 4; ++i) {
        float4 o;
        o.x = c[i][0] + bias.x; o.y = c[i][1] + bias.y;
        o.z = c[i][2] + bias.z; o.w = c[i][3] + bias.w;
        *(float4*)(C + (size_t)(m0 + ty * 4 + i) * GATES + col) = o;
    }
}

// ---------------- persistent recurrence ----------------
// 256 WGs x 512 thr. WG owns hidden [8b,8b+8) = 32 gate rows.
// kc=t&127 (k subset {g*128+kc}), rg=t>>7 gate group, 8 rows each.
// Waves 0-1 poll + rebroadcast via LDS; tail (reduce/gates/publish) on wave 0.
template<int USE_XG>
__global__ __launch_bounds__(NTHR, 2) void lstm_rec(
    const float* __restrict__ X,
    const float* __restrict__ Wih,
    const float* __restrict__ xg,
    const float* __restrict__ Whh,
    const float* __restrict__ bih,
    const float* __restrict__ bhh,
    unsigned long long* __restrict__ hcom)
{
    const int t  = threadIdx.x;
    const int kc = t & 127;
    const int rg = t >> 7;
    const int j0 = blockIdx.x * 8;

    // register-resident W_hh slice, packed as float2 pairs over g
    v2f whh2[8][8];
#pragma unroll
    for (int m = 0; m < 8; ++m) {
        const float* wr = Whh + (size_t)(rg * HID + j0 + m) * HID + kc;
#pragma unroll
        for (int j = 0; j < 8; ++j) {
            v2f p; p.x = wr[(2 * j) * 128]; p.y = wr[(2 * j + 1) * 128];
            whh2[m][j] = p;
        }
    }
    float wih[8][4];
    if (!USE_XG) {
#pragma unroll
        for (int m = 0; m < 8; ++m) {
            float4 vx = *(const float4*)(Wih + (size_t)(rg * HID + j0 + m) * KIN + kc * 4);
            wih[m][0] = vx.x; wih[m][1] = vx.y; wih[m][2] = vx.z; wih[m][3] = vx.w;
        }
    }

    float brow = 0.f;
    if (t < 32) {
        const int grow = (t >> 3) * HID + j0 + (t & 7);
        brow = bih[grow] + bhh[grow];
    }

    __shared__ float hshare[HID];
    __shared__ float part[32 * 132];
    float c_state = 0.f;

    for (int s = 0; s < T_STEPS; ++s) {
        // prefetch xg (reducer rows) before the poll — hides HBM/LLC latency
        float xgv = 0.f;
        if (USE_XG && t < 32)
            xgv = xg[(size_t)s * GATES + (t >> 3) * HID + j0 + (t & 7)];

        v2f hv2[8];
        if (t < 128) {
            // waves 0-1: sticky poll of 16 tagged words (parity s&1).
            // Monotone tags => chunks valid once stay valid; later rounds
            // only re-load stragglers (less MALL contention + finer grain).
            const unsigned long long* hp = hcom + (size_t)(s & 1) * HID;
            unsigned long long v[16];
            int pend = 0xffff;
            int guard = 1 << 18;
            for (;;) {
#pragma unroll
                for (int g = 0; g < 16; ++g) {
                    if (pend & (1 << g))
                        v[g] = __hip_atomic_load(hp + g * 128 + kc, __ATOMIC_RELAXED,
                                                 __HIP_MEMORY_SCOPE_AGENT);
                }
                int np = 0;
#pragma unroll
                for (int g = 0; g < 16; ++g)
                    if ((unsigned int)v[g] < (unsigned int)s) np |= (1 << g);
                pend = np;
                if (!np || --guard <= 0) break;
                __builtin_amdgcn_s_sleep(1);   // rate-limit the poll storm
            }
#pragma unroll
            for (int j = 0; j < 8; ++j) {
                v2f p;
                p.x = u2f((unsigned int)(v[2 * j] >> 32));
                p.y = u2f((unsigned int)(v[2 * j + 1] >> 32));
                hv2[j] = p;
                hshare[(2 * j) * 128 + kc]     = p.x;
                hshare[(2 * j + 1) * 128 + kc] = p.y;
            }
        }
        __syncthreads();                     // B1: hshare ready
        if (t >= 128) {
#pragma unroll
            for (int j = 0; j < 8; ++j) {
                v2f p;
                p.x = hshare[(2 * j) * 128 + kc];
                p.y = hshare[(2 * j + 1) * 128 + kc];
                hv2[j] = p;
            }
        }

        v2f acc2[8];
        if (!USE_XG) {
            float4 x4 = *(const float4*)(X + (size_t)s * KIN + kc * 4);
#pragma unroll
            for (int m = 0; m < 8; ++m) {
                float a = wih[m][0] * x4.x;
                a = fmaf(wih[m][1], x4.y, a);
                a = fmaf(wih[m][2], x4.z, a);
                a = fmaf(wih[m][3], x4.w, a);
                v2f z; z.x = a; z.y = 0.f; acc2[m] = z;
            }
        } else {
#pragma unroll
            for (int m = 0; m < 8; ++m) { v2f z; z.x = 0.f; z.y = 0.f; acc2[m] = z; }
        }

        // packed dot: 64 v_pk_fma_f32 per thread
#pragma unroll
        for (int m = 0; m < 8; ++m) {
            v2f a = acc2[m];
#pragma unroll
            for (int j = 0; j < 8; ++j)
                a = __builtin_elementwise_fma(whh2[m][j], hv2[j], a);
            acc2[m] = a;
        }
#pragma unroll
        for (int m = 0; m < 8; ++m)
            part[(rg * 8 + m) * 132 + kc] = acc2[m].x + acc2[m].y;
        __syncthreads();                     // B2: partials ready

        // tail: 64 threads reduce (2 per row), shuffle combine, 8 threads gate
        if (t < 64) {
            const int row = t & 31, half = t >> 5;
            const float4* p4 = (const float4*)(part + row * 132 + half * 64);
            float s0 = 0.f, s1 = 0.f, s2 = 0.f, s3 = 0.f;
#pragma unroll
            for (int i = 0; i < 16; ++i) {
                float4 pv = p4[i];
                s0 += pv.x; s1 += pv.y; s2 += pv.z; s3 += pv.w;
            }
            float sum = (s0 + s1) + (s2 + s3);
            sum += __shfl_xor(sum, 32, 64);  // combine the two halves
            sum += brow + xgv;               // valid on t<32 (rows)
            const float a1 = __shfl_down(sum, 8, 64);
            const float a2 = __shfl_down(sum, 16, 64);
            const float a3 = __shfl_down(sum, 24, 64);
            if (t < 8) {
                const float i_s = fast_sigmoid(sum);   // gate i (row t)
                const float f_s = fast_sigmoid(a1);    // gate f (row 8+t)
                const float g_t = fast_tanh(a2);       // gate g (row 16+t)
                const float o_s = fast_sigmoid(a3);    // gate o (row 24+t)
                c_state = f_s * c_state + i_s * g_t;
                const float h = o_s * fast_tanh(c_state);
                const unsigned long long pk =
                    ((unsigned long long)__float_as_uint(h) << 32) | (unsigned int)(s + 1);
                __hip_atomic_store(&hcom[(size_t)((s + 1) & 1) * HID + j0 + t], pk,
                                   __ATOMIC_RELAXED, __HIP_MEMORY_SCOPE_AGENT);
            }
        }
        // reuse safety: part(s+1)/hshare(s+1) writes are gated by poll(s+1),
        // which requires OWN publish(s+1), which happens after all reads of
        // part(s); hshare(s) reads precede B2(s).
    }
}

// ---------------- out[0] = h_T . W_lin + b_lin ----------------
__global__ __launch_bounds__(256) void final_linear(const unsigned long long* __restrict__ hcom,
                                                    const float* __restrict__ Wlin,
                                                    const float* __restrict__ blin,
                                                    float* __restrict__ out) {
    __shared__ float red[4];
    const int t = threadIdx.x;
    float a = 0.f;
#pragma unroll
    for (int e = 0; e < 8; ++e) {
        const int idx = t * 8 + e;
        a = fmaf(Wlin[idx], u2f((unsigned int)(hcom[idx] >> 32)), a);
    }
#pragma unroll
    for (int m = 1; m < 64; m <<= 1) a += __shfl_xor(a, m, 64);
    if ((t & 63) == 0) red[t >> 6] = a;
    __syncthreads();
    if (t == 0) out[0] = red[0] + red[1] + red[2] + red[3] + blin[0];
}

extern "C" void kernel_launch(void* const* d_in, const int* in_sizes, int n_in,
                              void* d_out, int out_size, void* d_ws, size_t ws_size,
                              hipStream_t stream) {
    const float* X    = (const float*)d_in[0];
    const float* Wih  = (const float*)d_in[1];
    const float* Whh  = (const float*)d_in[2];
    const float* bih  = (const float*)d_in[3];
    const float* bhh  = (const float*)d_in[4];
    const float* Wlin = (const float*)d_in[5];
    const float* blin = (const float*)d_in[6];
    float* out = (float*)d_out;

    char* ws = (char*)d_ws;
    const bool big = ws_size >= XG_BYTES + HCOM_BYTES;

    if (big) {
        float* xg = (float*)ws;
        unsigned long long* hcom = (unsigned long long*)(ws + XG_BYTES);
        (void)hipMemsetAsync(hcom, 0, HCOM_BYTES, stream);
        gemm_xg<<<dim3(GATES / 64, T_STEPS / 64), 256, 0, stream>>>(X, Wih, bih, bhh, xg);
        lstm_rec<1><<<dim3(NWG), dim3(NTHR), 0, stream>>>(X, Wih, xg, Whh, bih, bhh, hcom);
        final_linear<<<1, 256, 0, stream>>>(hcom, Wlin, blin, out);
    } else {
        unsigned long long* hcom = (unsigned long long*)ws;
        (void)hipMemsetAsync(hcom, 0, HCOM_BYTES, stream);
        lstm_rec<0><<<dim3(NWG), dim3(NTHR), 0, stream>>>(X, Wih, nullptr, Whh, bih, bhh, hcom);
        final_linear<<<1, 256, 0, stream>>>(hcom, Wlin, blin, out);
    }
}

// Round 10
// 11702.801 us; speedup vs baseline: 5.4387x; 1.0885x over previous
//
#include <hip/hip_runtime.h>

// LSTM T=4096, I=512, H=2048, 4H=8192, O=1, fp32.
// R10 = R7 (simple 16-load poll on waves 0-1, s_sleep(1) rounds, fast_tanh)
//  + tail (reduce/gates/publish) moved to wave 2 (non-poller) so pollers go
//    B2 -> poll(s+1) with zero intervening work
//  + s_sleep(8) before the FIRST poll round of each step (don't storm the
//    hcom lines during the publish window — R6 lesson).
// R9 lesson: predicated (sticky) polls add VALU to the discovery path; keep
// the poll round dead-simple. R8 lesson: 1024-thr WGs spill weights.
// h published as tagged u64 (fp32bits<<32 | step), parity double buffer.

#define T_STEPS 4096
#define HID     2048
#define GATES   8192
#define KIN     512
#define NWG     256
#define NTHR    512
#define XG_BYTES ((size_t)T_STEPS * GATES * 4)
#define HCOM_BYTES (2UL * HID * 8UL)

typedef float v2f __attribute__((ext_vector_type(2)));

__device__ __forceinline__ float u2f(unsigned int u) {
    union { unsigned int u; float f; } x; x.u = u; return x.f;
}
__device__ __forceinline__ float fast_sigmoid(float x) {
    return 1.f / (1.f + __expf(-x));
}
__device__ __forceinline__ float fast_tanh(float x) {
    return 2.f / (1.f + __expf(-2.f * x)) - 1.f;
}

// ---------------- xg = X @ Wih^T + (bih+bhh), fp32 tiled ----------------
__global__ __launch_bounds__(256) void gemm_xg(const float* __restrict__ A,
                                               const float* __restrict__ B,
                                               const float* __restrict__ bih,
                                               const float* __restrict__ bhh,
                                               float* __restrict__ C) {
    __shared__ float As[32][68];
    __shared__ float Bs[32][68];
    const int t  = threadIdx.x;
    const int tx = t & 15, ty = t >> 4;
    const int m0 = blockIdx.y * 64, n0 = blockIdx.x * 64;
    const int sr = t >> 3, sc = (t & 7) * 4;

    float c[4][4] = {};
    for (int k0 = 0; k0 < KIN; k0 += 32) {
        float4 a0 = *(const float4*)(A + (size_t)(m0 + sr)      * KIN + k0 + sc);
        float4 a1 = *(const float4*)(A + (size_t)(m0 + sr + 32) * KIN + k0 + sc);
        float4 b0 = *(const float4*)(B + (size_t)(n0 + sr)      * KIN + k0 + sc);
        float4 b1 = *(const float4*)(B + (size_t)(n0 + sr + 32) * KIN + k0 + sc);
        __syncthreads();
        As[sc+0][sr] = a0.x; As[sc+1][sr] = a0.y; As[sc+2][sr] = a0.z; As[sc+3][sr] = a0.w;
        As[sc+0][sr+32] = a1.x; As[sc+1][sr+32] = a1.y; As[sc+2][sr+32] = a1.z; As[sc+3][sr+32] = a1.w;
        Bs[sc+0][sr] = b0.x; Bs[sc+1][sr] = b0.y; Bs[sc+2][sr] = b0.z; Bs[sc+3][sr] = b0.w;
        Bs[sc+0][sr+32] = b1.x; Bs[sc+1][sr+32] = b1.y; Bs[sc+2][sr+32] = b1.z; Bs[sc+3][sr+32] = b1.w;
        __syncthreads();
#pragma unroll
        for (int kk = 0; kk < 32; ++kk) {
            float4 av = *(const float4*)&As[kk][ty * 4];
            float4 bv = *(const float4*)&Bs[kk][tx * 4];
            c[0][0] = fmaf(av.x, bv.x, c[0][0]); c[0][1] = fmaf(av.x, bv.y, c[0][1]);
            c[0][2] = fmaf(av.x, bv.z, c[0][2]); c[0][3] = fmaf(av.x, bv.w, c[0][3]);
            c[1][0] = fmaf(av.y, bv.x, c[1][0]); c[1][1] = fmaf(av.y, bv.y, c[1][1]);
            c[1][2] = fmaf(av.y, bv.z, c[1][2]); c[1][3] = fmaf(av.y, bv.w, c[1][3]);
            c[2][0] = fmaf(av.z, bv.x, c[2][0]); c[2][1] = fmaf(av.z, bv.y, c[2][1]);
            c[2][2] = fmaf(av.z, bv.z, c[2][2]); c[2][3] = fmaf(av.z, bv.w, c[2][3]);
            c[3][0] = fmaf(av.w, bv.x, c[3][0]); c[3][1] = fmaf(av.w, bv.y, c[3][1]);
            c[3][2] = fmaf(av.w, bv.z, c[3][2]); c[3][3] = fmaf(av.w, bv.w, c[3][3]);
        }
    }
    const int col = n0 + tx * 4;
    float4 bias;
    bias.x = bih[col]   + bhh[col];
    bias.y = bih[col+1] + bhh[col+1];
    bias.z = bih[col+2] + bhh[col+2];
    bias.w = bih[col+3] + bhh[col+3];
#pragma unroll
    for (int i = 0; i < 4; ++i) {
        float4 o;
        o.x = c[i][0] + bias.x; o.y = c[i][1] + bias.y;
        o.z = c[i][2] + bias.z; o.w = c[i][3] + bias.w;
        *(float4*)(C + (size_t)(m0 + ty * 4 + i) * GATES + col) = o;
    }
}

// ---------------- persistent recurrence ----------------
// 256 WGs x 512 thr. WG owns hidden [8b,8b+8) = 32 gate rows.
// kc=t&127 (k subset {g*128+kc}), rg=t>>7 gate group, 8 rows each.
// Waves 0-1: poll + LDS rebroadcast. Wave 2: tail (reduce/gates/publish).
template<int USE_XG>
__global__ __launch_bounds__(NTHR, 2) void lstm_rec(
    const float* __restrict__ X,
    const float* __restrict__ Wih,
    const float* __restrict__ xg,
    const float* __restrict__ Whh,
    const float* __restrict__ bih,
    const float* __restrict__ bhh,
    unsigned long long* __restrict__ hcom)
{
    const int t  = threadIdx.x;
    const int kc = t & 127;
    const int rg = t >> 7;
    const int j0 = blockIdx.x * 8;
    const int u  = t - 128;          // tail-wave local index (valid t in [128,192))

    // register-resident W_hh slice, packed as float2 pairs over g
    v2f whh2[8][8];
#pragma unroll
    for (int m = 0; m < 8; ++m) {
        const float* wr = Whh + (size_t)(rg * HID + j0 + m) * HID + kc;
#pragma unroll
        for (int j = 0; j < 8; ++j) {
            v2f p; p.x = wr[(2 * j) * 128]; p.y = wr[(2 * j + 1) * 128];
            whh2[m][j] = p;
        }
    }
    float wih[8][4];
    if (!USE_XG) {
#pragma unroll
        for (int m = 0; m < 8; ++m) {
            float4 vx = *(const float4*)(Wih + (size_t)(rg * HID + j0 + m) * KIN + kc * 4);
            wih[m][0] = vx.x; wih[m][1] = vx.y; wih[m][2] = vx.z; wih[m][3] = vx.w;
        }
    }

    // tail wave (wave 2): bias for local row u (u<32)
    float brow = 0.f;
    int growt = 0;
    if (t >= 128 && t < 160) {
        growt = (u >> 3) * HID + j0 + (u & 7);
        brow = bih[growt] + bhh[growt];
    }

    __shared__ float hshare[HID];
    __shared__ float part[32 * 132];
    float c_state = 0.f;

    for (int s = 0; s < T_STEPS; ++s) {
        // tail rows prefetch xg before everything (hides HBM/LLC latency)
        float xgv = 0.f;
        if (USE_XG && t >= 128 && t < 160)
            xgv = xg[(size_t)s * GATES + growt];

        v2f hv2[8];
        if (t < 128) {
            // waves 0-1 poll their 16 tagged words (parity s&1).
            // Initial sleep: let the publish window pass before storming the
            // lines with reads (R6 lesson). Then simple full-batch rounds.
            const unsigned long long* hp = hcom + (size_t)(s & 1) * HID;
            unsigned long long v[16];
            if (s > 0) __builtin_amdgcn_s_sleep(8);
            int guard = 1 << 18;
            for (;;) {
#pragma unroll
                for (int g = 0; g < 16; ++g)
                    v[g] = __hip_atomic_load(hp + g * 128 + kc, __ATOMIC_RELAXED,
                                             __HIP_MEMORY_SCOPE_AGENT);
                bool ok = true;
#pragma unroll
                for (int g = 0; g < 16; ++g)
                    ok &= ((unsigned int)v[g] >= (unsigned int)s);
                if (ok || --guard <= 0) break;
                __builtin_amdgcn_s_sleep(1);   // rate-limit the poll storm
            }
#pragma unroll
            for (int j = 0; j < 8; ++j) {
                v2f p;
                p.x = u2f((unsigned int)(v[2 * j] >> 32));
                p.y = u2f((unsigned int)(v[2 * j + 1] >> 32));
                hv2[j] = p;
                hshare[(2 * j) * 128 + kc]     = p.x;
                hshare[(2 * j + 1) * 128 + kc] = p.y;
            }
        }
        __syncthreads();                     // B1: hshare ready
        if (t >= 128) {
#pragma unroll
            for (int j = 0; j < 8; ++j) {
                v2f p;
                p.x = hshare[(2 * j) * 128 + kc];
                p.y = hshare[(2 * j + 1) * 128 + kc];
                hv2[j] = p;
            }
        }

        v2f acc2[8];
        if (!USE_XG) {
            float4 x4 = *(const float4*)(X + (size_t)s * KIN + kc * 4);
#pragma unroll
            for (int m = 0; m < 8; ++m) {
                float a = wih[m][0] * x4.x;
                a = fmaf(wih[m][1], x4.y, a);
                a = fmaf(wih[m][2], x4.z, a);
                a = fmaf(wih[m][3], x4.w, a);
                v2f z; z.x = a; z.y = 0.f; acc2[m] = z;
            }
        } else {
#pragma unroll
            for (int m = 0; m < 8; ++m) { v2f z; z.x = 0.f; z.y = 0.f; acc2[m] = z; }
        }

        // packed dot: 64 v_pk_fma_f32 per thread
#pragma unroll
        for (int m = 0; m < 8; ++m) {
            v2f a = acc2[m];
#pragma unroll
            for (int j = 0; j < 8; ++j)
                a = __builtin_elementwise_fma(whh2[m][j], hv2[j], a);
            acc2[m] = a;
        }
#pragma unroll
        for (int m = 0; m < 8; ++m)
            part[(rg * 8 + m) * 132 + kc] = acc2[m].x + acc2[m].y;
        __syncthreads();                     // B2: partials ready
        // waves 0-1 loop straight back to poll(s+1); wave 2 does the tail.

        if (t >= 128 && t < 192) {
            const int row = u & 31, half = u >> 5;
            const float4* p4 = (const float4*)(part + row * 132 + half * 64);
            float s0 = 0.f, s1 = 0.f, s2 = 0.f, s3 = 0.f;
#pragma unroll
            for (int i = 0; i < 16; ++i) {
                float4 pv = p4[i];
                s0 += pv.x; s1 += pv.y; s2 += pv.z; s3 += pv.w;
            }
            float sum = (s0 + s1) + (s2 + s3);
            sum += __shfl_xor(sum, 32, 64);  // combine the two halves
            sum += brow + xgv;               // valid on u<32 (rows)
            const float a1 = __shfl_down(sum, 8, 64);
            const float a2 = __shfl_down(sum, 16, 64);
            const float a3 = __shfl_down(sum, 24, 64);
            if (u < 8) {
                const float i_s = fast_sigmoid(sum);   // gate i (row u)
                const float f_s = fast_sigmoid(a1);    // gate f (row 8+u)
                const float g_t = fast_tanh(a2);       // gate g (row 16+u)
                const float o_s = fast_sigmoid(a3);    // gate o (row 24+u)
                c_state = f_s * c_state + i_s * g_t;
                const float h = o_s * fast_tanh(c_state);
                const unsigned long long pk =
                    ((unsigned long long)__float_as_uint(h) << 32) | (unsigned int)(s + 1);
                __hip_atomic_store(&hcom[(size_t)((s + 1) & 1) * HID + j0 + u], pk,
                                   __ATOMIC_RELAXED, __HIP_MEMORY_SCOPE_AGENT);
            }
        }
        // Reuse safety: hshare(s+1)/part(s+1) writes require poll(s+1) success
        // (needs OUR wave-2 publish(s+1), issued after its part(s) reads) or
        // B1(s+1) (requires wave 2's arrival after the tail). hshare(s) reads
        // by all dot waves precede their B2(s) arrival.
    }
}

// ---------------- out[0] = h_T . W_lin + b_lin ----------------
__global__ __launch_bounds__(256) void final_linear(const unsigned long long* __restrict__ hcom,
                                                    const float* __restrict__ Wlin,
                                                    const float* __restrict__ blin,
                                                    float* __restrict__ out) {
    __shared__ float red[4];
    const int t = threadIdx.x;
    float a = 0.f;
#pragma unroll
    for (int e = 0; e < 8; ++e) {
        const int idx = t * 8 + e;
        a = fmaf(Wlin[idx], u2f((unsigned int)(hcom[idx] >> 32)), a);
    }
#pragma unroll
    for (int m = 1; m < 64; m <<= 1) a += __shfl_xor(a, m, 64);
    if ((t & 63) == 0) red[t >> 6] = a;
    __syncthreads();
    if (t == 0) out[0] = red[0] + red[1] + red[2] + red[3] + blin[0];
}

extern "C" void kernel_launch(void* const* d_in, const int* in_sizes, int n_in,
                              void* d_out, int out_size, void* d_ws, size_t ws_size,
                              hipStream_t stream) {
    const float* X    = (const float*)d_in[0];
    const float* Wih  = (const float*)d_in[1];
    const float* Whh  = (const float*)d_in[2];
    const float* bih  = (const float*)d_in[3];
    const float* bhh  = (const float*)d_in[4];
    const float* Wlin = (const float*)d_in[5];
    const float* blin = (const float*)d_in[6];
    float* out = (float*)d_out;

    char* ws = (char*)d_ws;
    const bool big = ws_size >= XG_BYTES + HCOM_BYTES;

    if (big) {
        float* xg = (float*)ws;
        unsigned long long* hcom = (unsigned long long*)(ws + XG_BYTES);
        (void)hipMemsetAsync(hcom, 0, HCOM_BYTES, stream);
        gemm_xg<<<dim3(GATES / 64, T_STEPS / 64), 256, 0, stream>>>(X, Wih, bih, bhh, xg);
        lstm_rec<1><<<dim3(NWG), dim3(NTHR), 0, stream>>>(X, Wih, xg, Whh, bih, bhh, hcom);
        final_linear<<<1, 256, 0, stream>>>(hcom, Wlin, blin, out);
    } else {
        unsigned long long* hcom = (unsigned long long*)ws;
        (void)hipMemsetAsync(hcom, 0, HCOM_BYTES, stream);
        lstm_rec<0><<<dim3(NWG), dim3(NTHR), 0, stream>>>(X, Wih, nullptr, Whh, bih, bhh, hcom);
        final_linear<<<1, 256, 0, stream>>>(hcom, Wlin, blin, out);
    }
}

// Round 11
// 10565.348 us; speedup vs baseline: 6.0242x; 1.1077x over previous
//
#include <hip/hip_runtime.h>

// LSTM T=4096, I=512, H=2048, 4H=8192, O=1, fp32.
// R11 = R7 exactly (tail on wave 0, simple 16-load poll rounds, s_sleep(1),
// fast_tanh) + ONE change: wave 1 sleeps s_sleep(8) (~0.2 us) before its
// FIRST poll round each step, so it doesn't read-storm the hcom lines during
// the publish window (wave 0's tail already provides that delay for itself).
// Lessons: R6/R10 — early polling during publish window is net-negative;
// R8 — 1024-thr WGs spill weights; R9 — predicated polls add critical VALU.
// h published as tagged u64 (fp32bits<<32 | step), parity double buffer.

#define T_STEPS 4096
#define HID     2048
#define GATES   8192
#define KIN     512
#define NWG     256
#define NTHR    512
#define XG_BYTES ((size_t)T_STEPS * GATES * 4)
#define HCOM_BYTES (2UL * HID * 8UL)

typedef float v2f __attribute__((ext_vector_type(2)));

__device__ __forceinline__ float u2f(unsigned int u) {
    union { unsigned int u; float f; } x; x.u = u; return x.f;
}
__device__ __forceinline__ float fast_sigmoid(float x) {
    return 1.f / (1.f + __expf(-x));
}
__device__ __forceinline__ float fast_tanh(float x) {
    return 2.f / (1.f + __expf(-2.f * x)) - 1.f;
}

// ---------------- xg = X @ Wih^T + (bih+bhh), fp32 tiled ----------------
__global__ __launch_bounds__(256) void gemm_xg(const float* __restrict__ A,
                                               const float* __restrict__ B,
                                               const float* __restrict__ bih,
                                               const float* __restrict__ bhh,
                                               float* __restrict__ C) {
    __shared__ float As[32][68];
    __shared__ float Bs[32][68];
    const int t  = threadIdx.x;
    const int tx = t & 15, ty = t >> 4;
    const int m0 = blockIdx.y * 64, n0 = blockIdx.x * 64;
    const int sr = t >> 3, sc = (t & 7) * 4;

    float c[4][4] = {};
    for (int k0 = 0; k0 < KIN; k0 += 32) {
        float4 a0 = *(const float4*)(A + (size_t)(m0 + sr)      * KIN + k0 + sc);
        float4 a1 = *(const float4*)(A + (size_t)(m0 + sr + 32) * KIN + k0 + sc);
        float4 b0 = *(const float4*)(B + (size_t)(n0 + sr)      * KIN + k0 + sc);
        float4 b1 = *(const float4*)(B + (size_t)(n0 + sr + 32) * KIN + k0 + sc);
        __syncthreads();
        As[sc+0][sr] = a0.x; As[sc+1][sr] = a0.y; As[sc+2][sr] = a0.z; As[sc+3][sr] = a0.w;
        As[sc+0][sr+32] = a1.x; As[sc+1][sr+32] = a1.y; As[sc+2][sr+32] = a1.z; As[sc+3][sr+32] = a1.w;
        Bs[sc+0][sr] = b0.x; Bs[sc+1][sr] = b0.y; Bs[sc+2][sr] = b0.z; Bs[sc+3][sr] = b0.w;
        Bs[sc+0][sr+32] = b1.x; Bs[sc+1][sr+32] = b1.y; Bs[sc+2][sr+32] = b1.z; Bs[sc+3][sr+32] = b1.w;
        __syncthreads();
#pragma unroll
        for (int kk = 0; kk < 32; ++kk) {
            float4 av = *(const float4*)&As[kk][ty * 4];
            float4 bv = *(const float4*)&Bs[kk][tx * 4];
            c[0][0] = fmaf(av.x, bv.x, c[0][0]); c[0][1] = fmaf(av.x, bv.y, c[0][1]);
            c[0][2] = fmaf(av.x, bv.z, c[0][2]); c[0][3] = fmaf(av.x, bv.w, c[0][3]);
            c[1][0] = fmaf(av.y, bv.x, c[1][0]); c[1][1] = fmaf(av.y, bv.y, c[1][1]);
            c[1][2] = fmaf(av.y, bv.z, c[1][2]); c[1][3] = fmaf(av.y, bv.w, c[1][3]);
            c[2][0] = fmaf(av.z, bv.x, c[2][0]); c[2][1] = fmaf(av.z, bv.y, c[2][1]);
            c[2][2] = fmaf(av.z, bv.z, c[2][2]); c[2][3] = fmaf(av.z, bv.w, c[2][3]);
            c[3][0] = fmaf(av.w, bv.x, c[3][0]); c[3][1] = fmaf(av.w, bv.y, c[3][1]);
            c[3][2] = fmaf(av.w, bv.z, c[3][2]); c[3][3] = fmaf(av.w, bv.w, c[3][3]);
        }
    }
    const int col = n0 + tx * 4;
    float4 bias;
    bias.x = bih[col]   + bhh[col];
    bias.y = bih[col+1] + bhh[col+1];
    bias.z = bih[col+2] + bhh[col+2];
    bias.w = bih[col+3] + bhh[col+3];
#pragma unroll
    for (int i = 0; i < 4; ++i) {
        float4 o;
        o.x = c[i][0] + bias.x; o.y = c[i][1] + bias.y;
        o.z = c[i][2] + bias.z; o.w = c[i][3] + bias.w;
        *(float4*)(C + (size_t)(m0 + ty * 4 + i) * GATES + col) = o;
    }
}

// ---------------- persistent recurrence ----------------
// 256 WGs x 512 thr. WG owns hidden [8b,8b+8) = 32 gate rows.
// kc=t&127 (k subset {g*128+kc}), rg=t>>7 gate group, 8 rows each.
// Waves 0-1 poll + rebroadcast via LDS; tail (reduce/gates/publish) on wave 0.
template<int USE_XG>
__global__ __launch_bounds__(NTHR, 2) void lstm_rec(
    const float* __restrict__ X,
    const float* __restrict__ Wih,
    const float* __restrict__ xg,
    const float* __restrict__ Whh,
    const float* __restrict__ bih,
    const float* __restrict__ bhh,
    unsigned long long* __restrict__ hcom)
{
    const int t  = threadIdx.x;
    const int kc = t & 127;
    const int rg = t >> 7;
    const int j0 = blockIdx.x * 8;

    // register-resident W_hh slice, packed as float2 pairs over g
    v2f whh2[8][8];
#pragma unroll
    for (int m = 0; m < 8; ++m) {
        const float* wr = Whh + (size_t)(rg * HID + j0 + m) * HID + kc;
#pragma unroll
        for (int j = 0; j < 8; ++j) {
            v2f p; p.x = wr[(2 * j) * 128]; p.y = wr[(2 * j + 1) * 128];
            whh2[m][j] = p;
        }
    }
    float wih[8][4];
    if (!USE_XG) {
#pragma unroll
        for (int m = 0; m < 8; ++m) {
            float4 vx = *(const float4*)(Wih + (size_t)(rg * HID + j0 + m) * KIN + kc * 4);
            wih[m][0] = vx.x; wih[m][1] = vx.y; wih[m][2] = vx.z; wih[m][3] = vx.w;
        }
    }

    float brow = 0.f;
    if (t < 32) {
        const int grow = (t >> 3) * HID + j0 + (t & 7);
        brow = bih[grow] + bhh[grow];
    }

    __shared__ float hshare[HID];
    __shared__ float part[32 * 132];
    float c_state = 0.f;

    for (int s = 0; s < T_STEPS; ++s) {
        // prefetch xg (reducer rows) before the poll — hides HBM/LLC latency
        float xgv = 0.f;
        if (USE_XG && t < 32)
            xgv = xg[(size_t)s * GATES + (t >> 3) * HID + j0 + (t & 7)];

        v2f hv2[8];
        if (t < 128) {
            // Wave 1 delays its first round past the publish window; wave 0's
            // tail provides that delay naturally. (R11's single change.)
            if (t >= 64 && s > 0) __builtin_amdgcn_s_sleep(8);
            // waves 0-1 poll their 16 tagged words (parity s&1)
            const unsigned long long* hp = hcom + (size_t)(s & 1) * HID;
            unsigned long long v[16];
            int guard = 1 << 18;
            for (;;) {
#pragma unroll
                for (int g = 0; g < 16; ++g)
                    v[g] = __hip_atomic_load(hp + g * 128 + kc, __ATOMIC_RELAXED,
                                             __HIP_MEMORY_SCOPE_AGENT);
                bool ok = true;
#pragma unroll
                for (int g = 0; g < 16; ++g)
                    ok &= ((unsigned int)v[g] >= (unsigned int)s);
                if (ok || --guard <= 0) break;
                __builtin_amdgcn_s_sleep(1);   // rate-limit the poll storm
            }
#pragma unroll
            for (int j = 0; j < 8; ++j) {
                v2f p;
                p.x = u2f((unsigned int)(v[2 * j] >> 32));
                p.y = u2f((unsigned int)(v[2 * j + 1] >> 32));
                hv2[j] = p;
                hshare[(2 * j) * 128 + kc]     = p.x;
                hshare[(2 * j + 1) * 128 + kc] = p.y;
            }
        }
        __syncthreads();                     // B1: hshare ready
        if (t >= 128) {
#pragma unroll
            for (int j = 0; j < 8; ++j) {
                v2f p;
                p.x = hshare[(2 * j) * 128 + kc];
                p.y = hshare[(2 * j + 1) * 128 + kc];
                hv2[j] = p;
            }
        }

        v2f acc2[8];
        if (!USE_XG) {
            float4 x4 = *(const float4*)(X + (size_t)s * KIN + kc * 4);
#pragma unroll
            for (int m = 0; m < 8; ++m) {
                float a = wih[m][0] * x4.x;
                a = fmaf(wih[m][1], x4.y, a);
                a = fmaf(wih[m][2], x4.z, a);
                a = fmaf(wih[m][3], x4.w, a);
                v2f z; z.x = a; z.y = 0.f; acc2[m] = z;
            }
        } else {
#pragma unroll
            for (int m = 0; m < 8; ++m) { v2f z; z.x = 0.f; z.y = 0.f; acc2[m] = z; }
        }

        // packed dot: 64 v_pk_fma_f32 per thread
#pragma unroll
        for (int m = 0; m < 8; ++m) {
            v2f a = acc2[m];
#pragma unroll
            for (int j = 0; j < 8; ++j)
                a = __builtin_elementwise_fma(whh2[m][j], hv2[j], a);
            acc2[m] = a;
        }
#pragma unroll
        for (int m = 0; m < 8; ++m)
            part[(rg * 8 + m) * 132 + kc] = acc2[m].x + acc2[m].y;
        __syncthreads();                     // B2: partials ready

        // tail: 64 threads reduce (2 per row), shuffle combine, 8 threads gate
        if (t < 64) {
            const int row = t & 31, half = t >> 5;
            const float4* p4 = (const float4*)(part + row * 132 + half * 64);
            float s0 = 0.f, s1 = 0.f, s2 = 0.f, s3 = 0.f;
#pragma unroll
            for (int i = 0; i < 16; ++i) {
                float4 pv = p4[i];
                s0 += pv.x; s1 += pv.y; s2 += pv.z; s3 += pv.w;
            }
            float sum = (s0 + s1) + (s2 + s3);
            sum += __shfl_xor(sum, 32, 64);  // combine the two halves
            sum += brow + xgv;               // valid on t<32 (rows)
            const float a1 = __shfl_down(sum, 8, 64);
            const float a2 = __shfl_down(sum, 16, 64);
            const float a3 = __shfl_down(sum, 24, 64);
            if (t < 8) {
                const float i_s = fast_sigmoid(sum);   // gate i (row t)
                const float f_s = fast_sigmoid(a1);    // gate f (row 8+t)
                const float g_t = fast_tanh(a2);       // gate g (row 16+t)
                const float o_s = fast_sigmoid(a3);    // gate o (row 24+t)
                c_state = f_s * c_state + i_s * g_t;
                const float h = o_s * fast_tanh(c_state);
                const unsigned long long pk =
                    ((unsigned long long)__float_as_uint(h) << 32) | (unsigned int)(s + 1);
                __hip_atomic_store(&hcom[(size_t)((s + 1) & 1) * HID + j0 + t], pk,
                                   __ATOMIC_RELAXED, __HIP_MEMORY_SCOPE_AGENT);
            }
        }
        // reuse safety: part(s+1)/hshare(s+1) writes are gated by poll(s+1),
        // which requires OWN publish(s+1), which happens after all reads of
        // part(s); hshare(s) reads precede B2(s).
    }
}

// ---------------- out[0] = h_T . W_lin + b_lin ----------------
__global__ __launch_bounds__(256) void final_linear(const unsigned long long* __restrict__ hcom,
                                                    const float* __restrict__ Wlin,
                                                    const float* __restrict__ blin,
                                                    float* __restrict__ out) {
    __shared__ float red[4];
    const int t = threadIdx.x;
    float a = 0.f;
#pragma unroll
    for (int e = 0; e < 8; ++e) {
        const int idx = t * 8 + e;
        a = fmaf(Wlin[idx], u2f((unsigned int)(hcom[idx] >> 32)), a);
    }
#pragma unroll
    for (int m = 1; m < 64; m <<= 1) a += __shfl_xor(a, m, 64);
    if ((t & 63) == 0) red[t >> 6] = a;
    __syncthreads();
    if (t == 0) out[0] = red[0] + red[1] + red[2] + red[3] + blin[0];
}

extern "C" void kernel_launch(void* const* d_in, const int* in_sizes, int n_in,
                              void* d_out, int out_size, void* d_ws, size_t ws_size,
                              hipStream_t stream) {
    const float* X    = (const float*)d_in[0];
    const float* Wih  = (const float*)d_in[1];
    const float* Whh  = (const float*)d_in[2];
    const float* bih  = (const float*)d_in[3];
    const float* bhh  = (const float*)d_in[4];
    const float* Wlin = (const float*)d_in[5];
    const float* blin = (const float*)d_in[6];
    float* out = (float*)d_out;

    char* ws = (char*)d_ws;
    const bool big = ws_size >= XG_BYTES + HCOM_BYTES;

    if (big) {
        float* xg = (float*)ws;
        unsigned long long* hcom = (unsigned long long*)(ws + XG_BYTES);
        (void)hipMemsetAsync(hcom, 0, HCOM_BYTES, stream);
        gemm_xg<<<dim3(GATES / 64, T_STEPS / 64), 256, 0, stream>>>(X, Wih, bih, bhh, xg);
        lstm_rec<1><<<dim3(NWG), dim3(NTHR), 0, stream>>>(X, Wih, xg, Whh, bih, bhh, hcom);
        final_linear<<<1, 256, 0, stream>>>(hcom, Wlin, blin, out);
    } else {
        unsigned long long* hcom = (unsigned long long*)ws;
        (void)hipMemsetAsync(hcom, 0, HCOM_BYTES, stream);
        lstm_rec<0><<<dim3(NWG), dim3(NTHR), 0, stream>>>(X, Wih, nullptr, Whh, bih, bhh, hcom);
        final_linear<<<1, 256, 0, stream>>>(hcom, Wlin, blin, out);
    }
}

// Round 12
// 10533.241 us; speedup vs baseline: 6.0426x; 1.0030x over previous
//
#include <hip/hip_runtime.h>

// LSTM T=4096, I=512, H=2048, 4H=8192, O=1, fp32.
// R12 = R11 + replicated h-mailbox (K=4): producers store h to 4 replicas,
// reader WG b polls only replica b&3 — cuts per-line reader pressure 4x.
// Keeps: tail on wave 0, simple 16-load poll, s_sleep(1) rounds, wave-1
// first-round backoff s_sleep(8), fast_tanh.
// h published as tagged u64 (fp32bits<<32 | step), parity double buffer.

#define T_STEPS 4096
#define HID     2048
#define GATES   8192
#define KIN     512
#define NWG     256
#define NTHR    512
#define NREP    4
#define XG_BYTES ((size_t)T_STEPS * GATES * 4)
#define HCOM_BYTES ((size_t)NREP * 2 * HID * 8)   // 128 KB

typedef float v2f __attribute__((ext_vector_type(2)));

__device__ __forceinline__ float u2f(unsigned int u) {
    union { unsigned int u; float f; } x; x.u = u; return x.f;
}
__device__ __forceinline__ float fast_sigmoid(float x) {
    return 1.f / (1.f + __expf(-x));
}
__device__ __forceinline__ float fast_tanh(float x) {
    return 2.f / (1.f + __expf(-2.f * x)) - 1.f;
}

// ---------------- xg = X @ Wih^T + (bih+bhh), fp32 tiled ----------------
__global__ __launch_bounds__(256) void gemm_xg(const float* __restrict__ A,
                                               const float* __restrict__ B,
                                               const float* __restrict__ bih,
                                               const float* __restrict__ bhh,
                                               float* __restrict__ C) {
    __shared__ float As[32][68];
    __shared__ float Bs[32][68];
    const int t  = threadIdx.x;
    const int tx = t & 15, ty = t >> 4;
    const int m0 = blockIdx.y * 64, n0 = blockIdx.x * 64;
    const int sr = t >> 3, sc = (t & 7) * 4;

    float c[4][4] = {};
    for (int k0 = 0; k0 < KIN; k0 += 32) {
        float4 a0 = *(const float4*)(A + (size_t)(m0 + sr)      * KIN + k0 + sc);
        float4 a1 = *(const float4*)(A + (size_t)(m0 + sr + 32) * KIN + k0 + sc);
        float4 b0 = *(const float4*)(B + (size_t)(n0 + sr)      * KIN + k0 + sc);
        float4 b1 = *(const float4*)(B + (size_t)(n0 + sr + 32) * KIN + k0 + sc);
        __syncthreads();
        As[sc+0][sr] = a0.x; As[sc+1][sr] = a0.y; As[sc+2][sr] = a0.z; As[sc+3][sr] = a0.w;
        As[sc+0][sr+32] = a1.x; As[sc+1][sr+32] = a1.y; As[sc+2][sr+32] = a1.z; As[sc+3][sr+32] = a1.w;
        Bs[sc+0][sr] = b0.x; Bs[sc+1][sr] = b0.y; Bs[sc+2][sr] = b0.z; Bs[sc+3][sr] = b0.w;
        Bs[sc+0][sr+32] = b1.x; Bs[sc+1][sr+32] = b1.y; Bs[sc+2][sr+32] = b1.z; Bs[sc+3][sr+32] = b1.w;
        __syncthreads();
#pragma unroll
        for (int kk = 0; kk < 32; ++kk) {
            float4 av = *(const float4*)&As[kk][ty * 4];
            float4 bv = *(const float4*)&Bs[kk][tx * 4];
            c[0][0] = fmaf(av.x, bv.x, c[0][0]); c[0][1] = fmaf(av.x, bv.y, c[0][1]);
            c[0][2] = fmaf(av.x, bv.z, c[0][2]); c[0][3] = fmaf(av.x, bv.w, c[0][3]);
            c[1][0] = fmaf(av.y, bv.x, c[1][0]); c[1][1] = fmaf(av.y, bv.y, c[1][1]);
            c[1][2] = fmaf(av.y, bv.z, c[1][2]); c[1][3] = fmaf(av.y, bv.w, c[1][3]);
            c[2][0] = fmaf(av.z, bv.x, c[2][0]); c[2][1] = fmaf(av.z, bv.y, c[2][1]);
            c[2][2] = fmaf(av.z, bv.z, c[2][2]); c[2][3] = fmaf(av.z, bv.w, c[2][3]);
            c[3][0] = fmaf(av.w, bv.x, c[3][0]); c[3][1] = fmaf(av.w, bv.y, c[3][1]);
            c[3][2] = fmaf(av.w, bv.z, c[3][2]); c[3][3] = fmaf(av.w, bv.w, c[3][3]);
        }
    }
    const int col = n0 + tx * 4;
    float4 bias;
    bias.x = bih[col]   + bhh[col];
    bias.y = bih[col+1] + bhh[col+1];
    bias.z = bih[col+2] + bhh[col+2];
    bias.w = bih[col+3] + bhh[col+3];
#pragma unroll
    for (int i = 0; i < 4; ++i) {
        float4 o;
        o.x = c[i][0] + bias.x; o.y = c[i][1] + bias.y;
        o.z = c[i][2] + bias.z; o.w = c[i][3] + bias.w;
        *(float4*)(C + (size_t)(m0 + ty * 4 + i) * GATES + col) = o;
    }
}

// ---------------- persistent recurrence ----------------
// 256 WGs x 512 thr. WG owns hidden [8b,8b+8) = 32 gate rows.
// kc=t&127 (k subset {g*128+kc}), rg=t>>7 gate group, 8 rows each.
// Waves 0-1 poll replica (wg&3) + rebroadcast via LDS; tail on wave 0.
// hcom layout: replica r, parity p at hcom + (r*2+p)*HID.
template<int USE_XG>
__global__ __launch_bounds__(NTHR, 2) void lstm_rec(
    const float* __restrict__ X,
    const float* __restrict__ Wih,
    const float* __restrict__ xg,
    const float* __restrict__ Whh,
    const float* __restrict__ bih,
    const float* __restrict__ bhh,
    unsigned long long* __restrict__ hcom)
{
    const int t  = threadIdx.x;
    const int kc = t & 127;
    const int rg = t >> 7;
    const int j0 = blockIdx.x * 8;
    const int rep = blockIdx.x & (NREP - 1);

    // register-resident W_hh slice, packed as float2 pairs over g
    v2f whh2[8][8];
#pragma unroll
    for (int m = 0; m < 8; ++m) {
        const float* wr = Whh + (size_t)(rg * HID + j0 + m) * HID + kc;
#pragma unroll
        for (int j = 0; j < 8; ++j) {
            v2f p; p.x = wr[(2 * j) * 128]; p.y = wr[(2 * j + 1) * 128];
            whh2[m][j] = p;
        }
    }
    float wih[8][4];
    if (!USE_XG) {
#pragma unroll
        for (int m = 0; m < 8; ++m) {
            float4 vx = *(const float4*)(Wih + (size_t)(rg * HID + j0 + m) * KIN + kc * 4);
            wih[m][0] = vx.x; wih[m][1] = vx.y; wih[m][2] = vx.z; wih[m][3] = vx.w;
        }
    }

    float brow = 0.f;
    if (t < 32) {
        const int grow = (t >> 3) * HID + j0 + (t & 7);
        brow = bih[grow] + bhh[grow];
    }

    __shared__ float hshare[HID];
    __shared__ float part[32 * 132];
    float c_state = 0.f;

    for (int s = 0; s < T_STEPS; ++s) {
        // prefetch xg (reducer rows) before the poll — hides HBM/LLC latency
        float xgv = 0.f;
        if (USE_XG && t < 32)
            xgv = xg[(size_t)s * GATES + (t >> 3) * HID + j0 + (t & 7)];

        v2f hv2[8];
        if (t < 128) {
            // Wave 1 delays its first round past the publish window; wave 0's
            // tail provides that delay naturally. (R11 lesson.)
            if (t >= 64 && s > 0) __builtin_amdgcn_s_sleep(8);
            // poll my replica's 16 tagged words (parity s&1)
            const unsigned long long* hp = hcom + ((size_t)rep * 2 + (s & 1)) * HID;
            unsigned long long v[16];
            int guard = 1 << 18;
            for (;;) {
#pragma unroll
                for (int g = 0; g < 16; ++g)
                    v[g] = __hip_atomic_load(hp + g * 128 + kc, __ATOMIC_RELAXED,
                                             __HIP_MEMORY_SCOPE_AGENT);
                bool ok = true;
#pragma unroll
                for (int g = 0; g < 16; ++g)
                    ok &= ((unsigned int)v[g] >= (unsigned int)s);
                if (ok || --guard <= 0) break;
                __builtin_amdgcn_s_sleep(1);   // rate-limit the poll storm
            }
#pragma unroll
            for (int j = 0; j < 8; ++j) {
                v2f p;
                p.x = u2f((unsigned int)(v[2 * j] >> 32));
                p.y = u2f((unsigned int)(v[2 * j + 1] >> 32));
                hv2[j] = p;
                hshare[(2 * j) * 128 + kc]     = p.x;
                hshare[(2 * j + 1) * 128 + kc] = p.y;
            }
        }
        __syncthreads();                     // B1: hshare ready
        if (t >= 128) {
#pragma unroll
            for (int j = 0; j < 8; ++j) {
                v2f p;
                p.x = hshare[(2 * j) * 128 + kc];
                p.y = hshare[(2 * j + 1) * 128 + kc];
                hv2[j] = p;
            }
        }

        v2f acc2[8];
        if (!USE_XG) {
            float4 x4 = *(const float4*)(X + (size_t)s * KIN + kc * 4);
#pragma unroll
            for (int m = 0; m < 8; ++m) {
                float a = wih[m][0] * x4.x;
                a = fmaf(wih[m][1], x4.y, a);
                a = fmaf(wih[m][2], x4.z, a);
                a = fmaf(wih[m][3], x4.w, a);
                v2f z; z.x = a; z.y = 0.f; acc2[m] = z;
            }
        } else {
#pragma unroll
            for (int m = 0; m < 8; ++m) { v2f z; z.x = 0.f; z.y = 0.f; acc2[m] = z; }
        }

        // packed dot: 64 v_pk_fma_f32 per thread
#pragma unroll
        for (int m = 0; m < 8; ++m) {
            v2f a = acc2[m];
#pragma unroll
            for (int j = 0; j < 8; ++j)
                a = __builtin_elementwise_fma(whh2[m][j], hv2[j], a);
            acc2[m] = a;
        }
#pragma unroll
        for (int m = 0; m < 8; ++m)
            part[(rg * 8 + m) * 132 + kc] = acc2[m].x + acc2[m].y;
        __syncthreads();                     // B2: partials ready

        // tail: 64 threads reduce (2 per row), shuffle combine, 8 threads gate
        if (t < 64) {
            const int row = t & 31, half = t >> 5;
            const float4* p4 = (const float4*)(part + row * 132 + half * 64);
            float s0 = 0.f, s1 = 0.f, s2 = 0.f, s3 = 0.f;
#pragma unroll
            for (int i = 0; i < 16; ++i) {
                float4 pv = p4[i];
                s0 += pv.x; s1 += pv.y; s2 += pv.z; s3 += pv.w;
            }
            float sum = (s0 + s1) + (s2 + s3);
            sum += __shfl_xor(sum, 32, 64);  // combine the two halves
            sum += brow + xgv;               // valid on t<32 (rows)
            const float a1 = __shfl_down(sum, 8, 64);
            const float a2 = __shfl_down(sum, 16, 64);
            const float a3 = __shfl_down(sum, 24, 64);
            if (t < 8) {
                const float i_s = fast_sigmoid(sum);   // gate i (row t)
                const float f_s = fast_sigmoid(a1);    // gate f (row 8+t)
                const float g_t = fast_tanh(a2);       // gate g (row 16+t)
                const float o_s = fast_sigmoid(a3);    // gate o (row 24+t)
                c_state = f_s * c_state + i_s * g_t;
                const float h = o_s * fast_tanh(c_state);
                const unsigned long long pk =
                    ((unsigned long long)__float_as_uint(h) << 32) | (unsigned int)(s + 1);
                const size_t slot = (size_t)((s + 1) & 1) * HID + j0 + t;
#pragma unroll
                for (int r = 0; r < NREP; ++r)
                    __hip_atomic_store(&hcom[(size_t)r * 2 * HID + slot], pk,
                                       __ATOMIC_RELAXED, __HIP_MEMORY_SCOPE_AGENT);
            }
        }
        // reuse safety (per replica): overwriting parity-p slot s with s+2
        // requires THIS WG to pass poll(s+1), which requires every WG
        // (incl. any reader still at step s) to have published s+1 — which
        // they only do after finishing step s. Same invariant as R11.
    }
}

// ---------------- out[0] = h_T . W_lin + b_lin ----------------
__global__ __launch_bounds__(256) void final_linear(const unsigned long long* __restrict__ hcom,
                                                    const float* __restrict__ Wlin,
                                                    const float* __restrict__ blin,
                                                    float* __restrict__ out) {
    __shared__ float red[4];
    const int t = threadIdx.x;
    float a = 0.f;
#pragma unroll
    for (int e = 0; e < 8; ++e) {
        const int idx = t * 8 + e;   // replica 0, parity 0 holds h_T (tag 4096)
        a = fmaf(Wlin[idx], u2f((unsigned int)(hcom[idx] >> 32)), a);
    }
#pragma unroll
    for (int m = 1; m < 64; m <<= 1) a += __shfl_xor(a, m, 64);
    if ((t & 63) == 0) red[t >> 6] = a;
    __syncthreads();
    if (t == 0) out[0] = red[0] + red[1] + red[2] + red[3] + blin[0];
}

extern "C" void kernel_launch(void* const* d_in, const int* in_sizes, int n_in,
                              void* d_out, int out_size, void* d_ws, size_t ws_size,
                              hipStream_t stream) {
    const float* X    = (const float*)d_in[0];
    const float* Wih  = (const float*)d_in[1];
    const float* Whh  = (const float*)d_in[2];
    const float* bih  = (const float*)d_in[3];
    const float* bhh  = (const float*)d_in[4];
    const float* Wlin = (const float*)d_in[5];
    const float* blin = (const float*)d_in[6];
    float* out = (float*)d_out;

    char* ws = (char*)d_ws;
    const bool big = ws_size >= XG_BYTES + HCOM_BYTES;

    if (big) {
        float* xg = (float*)ws;
        unsigned long long* hcom = (unsigned long long*)(ws + XG_BYTES);
        (void)hipMemsetAsync(hcom, 0, HCOM_BYTES, stream);
        gemm_xg<<<dim3(GATES / 64, T_STEPS / 64), 256, 0, stream>>>(X, Wih, bih, bhh, xg);
        lstm_rec<1><<<dim3(NWG), dim3(NTHR), 0, stream>>>(X, Wih, xg, Whh, bih, bhh, hcom);
        final_linear<<<1, 256, 0, stream>>>(hcom, Wlin, blin, out);
    } else {
        unsigned long long* hcom = (unsigned long long*)ws;
        (void)hipMemsetAsync(hcom, 0, HCOM_BYTES, stream);
        lstm_rec<0><<<dim3(NWG), dim3(NTHR), 0, stream>>>(X, Wih, nullptr, Whh, bih, bhh, hcom);
        final_linear<<<1, 256, 0, stream>>>(hcom, Wlin, blin, out);
    }
}